// Round 6
// baseline (634.457 us; speedup 1.0000x reference)
//
#include <hip/hip_runtime.h>
#include <hip/hip_bf16.h>
#include <math.h>

#define T_TOK 8192
#define E_NUM 8
#define GAP_TAU 2e-3f

typedef __attribute__((ext_vector_type(8))) short short8;
typedef __attribute__((ext_vector_type(4))) float floatx4;
typedef __attribute__((ext_vector_type(2))) unsigned int uintx2;

__device__ __forceinline__ unsigned short f2bf(float f) {
  unsigned int u = __builtin_bit_cast(unsigned int, f);
  u += 0x7fffu + ((u >> 16) & 1u);
  return (unsigned short)(u >> 16);
}

// async global->LDS, 16B per lane; LDS dest = wave-uniform base + lane*16
__device__ __forceinline__ void async16(const unsigned short* g, unsigned short* l) {
  __builtin_amdgcn_global_load_lds(
      (const __attribute__((address_space(1))) void*)g,
      (__attribute__((address_space(3))) void*)l, 16, 0, 0);
}

// ---------------- Router pass 1: fp32 logits, top-2, flag small-gap tokens ----
// Also emits xb (bf16 copy of x) as a fused side-product. xb is consumed by
// all XCDs (token gather) -> nontemporal store pushes it toward L3 clean
// instead of leaving dirty lines in the producer XCD's L2.
__global__ __launch_bounds__(256) void router_fp32_kernel(
    const float* __restrict__ x, const float* __restrict__ rw1,
    const float* __restrict__ rw2,
    int* __restrict__ tok_top, float* __restrict__ tok_w,
    int* __restrict__ fix_list, int* __restrict__ fix_cnt,
    unsigned short* __restrict__ xb) {
  __shared__ __align__(16) float xs[8][1024];  // 32 KB
  __shared__ float ph[128][8];                 // 4 KB
  __shared__ float hs[8][129];
  __shared__ float ls[8][8];
  const int t = threadIdx.x;
  const int tok0 = blockIdx.x * 8;

  {
    const float4* xsrc = (const float4*)(x + (size_t)tok0 * 1024);
    float4* xd = (float4*)&xs[0][0];
    uintx2* xbd = (uintx2*)(xb + (size_t)tok0 * 1024);
#pragma unroll
    for (int i = 0; i < 8; ++i) {
      float4 v = xsrc[t + i * 256];
      xd[t + i * 256] = v;
      ushort4 o;
      o.x = f2bf(v.x); o.y = f2bf(v.y); o.z = f2bf(v.z); o.w = f2bf(v.w);
      __builtin_nontemporal_store(__builtin_bit_cast(uintx2, o), &xbd[t + i * 256]);
    }
  }
  __syncthreads();

  const int j = t & 127, h = t >> 7;
  float acc[8];
#pragma unroll
  for (int tt = 0; tt < 8; ++tt) acc[tt] = 0.f;

  const int dbeg = h * 512, dend = dbeg + 512;
#pragma unroll 2
  for (int d0 = dbeg; d0 < dend; d0 += 4) {
    float w0 = rw1[(d0 + 0) * 128 + j];
    float w1 = rw1[(d0 + 1) * 128 + j];
    float w2 = rw1[(d0 + 2) * 128 + j];
    float w3 = rw1[(d0 + 3) * 128 + j];
    float4 xv[8];
#pragma unroll
    for (int tt = 0; tt < 8; ++tt) xv[tt] = *(const float4*)&xs[tt][d0];
#pragma unroll
    for (int tt = 0; tt < 8; ++tt) {
      acc[tt] = fmaf(xv[tt].x, w0, acc[tt]);
      acc[tt] = fmaf(xv[tt].y, w1, acc[tt]);
      acc[tt] = fmaf(xv[tt].z, w2, acc[tt]);
      acc[tt] = fmaf(xv[tt].w, w3, acc[tt]);
    }
  }
  if (h == 1) {
#pragma unroll
    for (int tt = 0; tt < 8; ++tt) ph[j][tt] = acc[tt];
  }
  __syncthreads();
  if (h == 0) {
#pragma unroll
    for (int tt = 0; tt < 8; ++tt) {
      float a = acc[tt] + ph[j][tt];
      hs[tt][j] = a / (1.f + expf(-a));
    }
  }
  __syncthreads();
  if (t < 64) {
    int tt = t >> 3, e = t & 7;
    float l = 0.f;
#pragma unroll 4
    for (int jj = 0; jj < 128; ++jj) l = fmaf(hs[tt][jj], rw2[jj * 8 + e], l);
    ls[tt][e] = l;
  }
  __syncthreads();
  if (t < 8) {
    int tt = t;
    float l[8];
#pragma unroll
    for (int e = 0; e < 8; ++e) l[e] = ls[tt][e];
    int i0 = 0;
#pragma unroll
    for (int e = 1; e < 8; ++e) if (l[e] > l[i0]) i0 = e;
    int i1 = (i0 == 0) ? 1 : 0;
#pragma unroll
    for (int e = 0; e < 8; ++e) if (e != i0 && l[e] > l[i1]) i1 = e;
    float v2 = -3.4e38f;
#pragma unroll
    for (int e = 0; e < 8; ++e) if (e != i0 && e != i1 && l[e] > v2) v2 = l[e];
    float gap = l[i1] - v2;
    float p = expf(l[i1] - l[i0]);
    float w0 = 1.f / (1.f + p);
    int tok = tok0 + tt;
    tok_top[2 * tok] = i0; tok_top[2 * tok + 1] = i1;
    tok_w[2 * tok] = w0;   tok_w[2 * tok + 1] = 1.f - w0;
    if (gap < GAP_TAU) { int pos = atomicAdd(fix_cnt, 1); fix_list[pos] = tok; }
  }
}

// ---------------- Router pass 2: exact fp64 recompute for flagged tokens ----
__global__ __launch_bounds__(256) void router_fix_kernel(
    const float* __restrict__ x, const float* __restrict__ rw1,
    const float* __restrict__ rw2, const int* __restrict__ fix_list,
    const int* __restrict__ fix_cnt,
    int* __restrict__ tok_top, float* __restrict__ tok_w) {
  __shared__ __align__(16) float xs[1024];
  __shared__ double red[128];
  __shared__ double hs[128];
  __shared__ double ls[8];
  const int t = threadIdx.x;
  const int nfix = *fix_cnt;
  for (int it = blockIdx.x; it < nfix; it += gridDim.x) {
    int tok = fix_list[it];
    ((float4*)xs)[t] = ((const float4*)(x + (size_t)tok * 1024))[t];
    __syncthreads();
    const int j = t & 127, h = t >> 7;
    double a0 = 0, a1 = 0, a2 = 0, a3 = 0;
    const int dbeg = h * 512;
    for (int d0 = dbeg; d0 < dbeg + 512; d0 += 4) {
      a0 = fma((double)xs[d0 + 0], (double)rw1[(d0 + 0) * 128 + j], a0);
      a1 = fma((double)xs[d0 + 1], (double)rw1[(d0 + 1) * 128 + j], a1);
      a2 = fma((double)xs[d0 + 2], (double)rw1[(d0 + 2) * 128 + j], a2);
      a3 = fma((double)xs[d0 + 3], (double)rw1[(d0 + 3) * 128 + j], a3);
    }
    double a = (a0 + a1) + (a2 + a3);
    if (h == 1) red[j] = a;
    __syncthreads();
    if (h == 0) {
      double s = a + red[j];
      hs[j] = s / (1.0 + exp(-s));
    }
    __syncthreads();
    if (t < 8) {
      int e = t;
      double l = 0;
      for (int jj = 0; jj < 128; ++jj) l = fma(hs[jj], (double)rw2[jj * 8 + e], l);
      ls[e] = l;
    }
    __syncthreads();
    if (t == 0) {
      double l[8];
#pragma unroll
      for (int e = 0; e < 8; ++e) l[e] = ls[e];
      int i0 = 0;
#pragma unroll
      for (int e = 1; e < 8; ++e) if (l[e] > l[i0]) i0 = e;
      int i1 = (i0 == 0) ? 1 : 0;
#pragma unroll
      for (int e = 0; e < 8; ++e) if (e != i0 && l[e] > l[i1]) i1 = e;
      double p = exp(l[i1] - l[i0]);
      double w0 = 1.0 / (1.0 + p);
      tok_top[2 * tok] = i0; tok_top[2 * tok + 1] = i1;
      tok_w[2 * tok] = (float)w0; tok_w[2 * tok + 1] = (float)(1.0 - w0);
    }
    __syncthreads();
  }
}

// ---------------- Scatter: build per-expert token lists (block-aggregated) ----
__global__ __launch_bounds__(256) void scatter_kernel(
    const int* __restrict__ tok_top, const float* __restrict__ tok_w,
    int* __restrict__ cnt, int* __restrict__ tid_list, float* __restrict__ tw_list) {
  __shared__ int hist[8], run[8];
  const int t = threadIdx.x;
  if (t < 8) hist[t] = 0;
  __syncthreads();
  const int tok = blockIdx.x * 256 + t;
  const int e0 = tok_top[2 * tok], e1 = tok_top[2 * tok + 1];
  atomicAdd(&hist[e0], 1);
  atomicAdd(&hist[e1], 1);
  __syncthreads();
  if (t < 8) run[t] = atomicAdd(&cnt[t], hist[t]);
  __syncthreads();
  int p0 = atomicAdd(&run[e0], 1);
  tid_list[e0 * T_TOK + p0] = tok; tw_list[e0 * T_TOK + p0] = tok_w[2 * tok];
  int p1 = atomicAdd(&run[e1], 1);
  tid_list[e1 * T_TOK + p1] = tok; tw_list[e1 * T_TOK + p1] = tok_w[2 * tok + 1];
}

__global__ void prefix_kernel(const int* __restrict__ cnt, int* __restrict__ base) {
  if (threadIdx.x == 0 && blockIdx.x == 0) {
    int s = 0;
    for (int e = 0; e < E_NUM; ++e) { base[e] = s; s += cnt[e]; }
  }
}

// ------- tiled transpose + convert, XCD-affine: [e][R][C] fp32 -> [e][C][R] bf16
// 1D grid, e = blockIdx&7 so expert-e's bf16 weights are produced ON XCD e and
// stay dirty-resident in its L2 for the gemm that reads them on the same XCD.
__global__ __launch_bounds__(256) void transpose_bf16_kernel(
    const float* __restrict__ in, unsigned short* __restrict__ out,
    int R, int C, int ylog) {
  __shared__ unsigned short tile[64][65];
  const int b = blockIdx.x;
  const int e = b & 7;
  const int t2 = b >> 3;
  const int r0 = (t2 & ((1 << ylog) - 1)) << 6;
  const int c0 = (t2 >> ylog) << 6;
  const float* src = in + (size_t)e * R * C;
  unsigned short* dst = out + (size_t)e * R * C;
  const int t = threadIdx.x;
  const int cc = (t & 15) * 4;
#pragma unroll
  for (int p = 0; p < 4; ++p) {
    int r = p * 16 + (t >> 4);
    float4 v = *(const float4*)(src + (size_t)(r0 + r) * C + c0 + cc);
    tile[cc + 0][r] = f2bf(v.x);
    tile[cc + 1][r] = f2bf(v.y);
    tile[cc + 2][r] = f2bf(v.z);
    tile[cc + 3][r] = f2bf(v.w);
  }
  __syncthreads();
#pragma unroll
  for (int p = 0; p < 4; ++p) {
    int fr = p * 16 + (t >> 4);
    ushort4 o;
    o.x = tile[fr][cc + 0]; o.y = tile[fr][cc + 1];
    o.z = tile[fr][cc + 2]; o.w = tile[fr][cc + 3];
    *(ushort4*)(dst + (size_t)(c0 + fr) * R + r0 + cc) = o;
  }
}

// ============ GEMM1: h[slot][f] = silu( x[tok][:] @ W1t[e][f][:] ) =============
// r0-exact inner loop (measured best). NEW: expert<->XCD affinity (e = blk&7)
// + hierarchical per-XCD order (nl inner, m mid, n-half outer) so the resident
// window's working set = half B-slab (2 MB) + streamed A -> fits 4 MB L2.
// Grid-stride loop guarantees coverage under arbitrary routing imbalance.
__global__ __launch_bounds__(256) void gemm1_kernel(
    const unsigned short* __restrict__ xb,   // [T][1024] bf16
    const unsigned short* __restrict__ w1t,  // [E][2048][1024] bf16
    const int* __restrict__ cnt, const int* __restrict__ base,
    const int* __restrict__ tid_list,
    unsigned short* __restrict__ h_buf) {    // [2T][2048] bf16
  __shared__ __align__(16) unsigned short As[128 * 64];
  __shared__ __align__(16) unsigned short Bs[128 * 64];

  const int e = blockIdx.x & 7;
  const int count = cnt[e];
  const int mt = (count + 127) >> 7;
  const int bs = base[e];

  const int t = threadIdx.x;
  const int wv = t >> 6, lane = t & 63;
  const int quad = lane >> 4, lr = lane & 15;
  const int wm = (wv & 1) * 64, wn = (wv >> 1) * 64;
  const int lr8 = lane >> 3, lc8 = lane & 7;
  const int chunk = lc8 ^ lr8;

  for (int idx = blockIdx.x >> 3; idx < mt * 16; idx += 352) {
    const int nl = idx & 7;         // n within half (8 of 16)
    int mr = idx >> 3;              // [0, 2*mt)
    int nh = 0;
    if (mr >= mt) { mr -= mt; nh = 1; }
    const int m0 = mr << 7;
    const int n0 = (nh * 8 + nl) << 7;

    const unsigned short* aptr[4];
    const unsigned short* bptr[4];
#pragma unroll
    for (int q = 0; q < 4; ++q) {
      int ar = m0 + wv * 32 + q * 8 + lr8;
      int ai = ar < count ? ar : count - 1;
      int tok = tid_list[e * T_TOK + ai];
      aptr[q] = xb + (size_t)tok * 1024 + chunk * 8;
      int br = n0 + wv * 32 + q * 8 + lr8;
      bptr[q] = w1t + ((size_t)e * 2048 + br) * 1024 + chunk * 8;
    }
    unsigned short* aldsb = &As[wv * 2048];
    unsigned short* bldsb = &Bs[wv * 2048];

    floatx4 zero = {0.f, 0.f, 0.f, 0.f};
    floatx4 acc[4][4];
#pragma unroll
    for (int i = 0; i < 4; ++i)
#pragma unroll
      for (int j = 0; j < 4; ++j) acc[i][j] = zero;

    for (int k0 = 0; k0 < 1024; k0 += 64) {
      __syncthreads();
#pragma unroll
      for (int q = 0; q < 4; ++q) {
        async16(aptr[q] + k0, aldsb + q * 512);
        async16(bptr[q] + k0, bldsb + q * 512);
      }
      __syncthreads();
#pragma unroll
      for (int ks = 0; ks < 2; ++ks) {
        short8 af[4], bfv[4];
#pragma unroll
        for (int i = 0; i < 4; ++i) {
          int r = wm + i * 16 + lr;
          int pc = (ks * 4 + quad) ^ (lr & 7);
          af[i] = *(const short8*)&As[r * 64 + pc * 8];
        }
#pragma unroll
        for (int j = 0; j < 4; ++j) {
          int r = wn + j * 16 + lr;
          int pc = (ks * 4 + quad) ^ (lr & 7);
          bfv[j] = *(const short8*)&Bs[r * 64 + pc * 8];
        }
#pragma unroll
        for (int i = 0; i < 4; ++i)
#pragma unroll
          for (int j = 0; j < 4; ++j)
            acc[i][j] = __builtin_amdgcn_mfma_f32_16x16x32_bf16(af[i], bfv[j], acc[i][j], 0, 0, 0);
      }
    }

#pragma unroll
    for (int i = 0; i < 4; ++i) {
#pragma unroll
      for (int r = 0; r < 4; ++r) {
        int grow = m0 + wm + i * 16 + quad * 4 + r;
        if (grow < count) {
          size_t rowoff = (size_t)(bs + grow) * 2048;
#pragma unroll
          for (int j = 0; j < 4; ++j) {
            float v = acc[i][j][r];
            float s = v / (1.0f + __expf(-v));
            h_buf[rowoff + n0 + wn + j * 16 + lr] = f2bf(s);
          }
        }
      }
    }
  }
}

// ============ GEMM2: out[tok][:] += w * ( h[slot][:] @ W2t[e][d][:] ) ==========
// Same affinity: expert-e blocks on XCD e read hbuf[e-slab] that gemm1 wrote
// on the SAME XCD (no cross-XCD dirty-L2 handoff) and w2t[e] (4 MB, L2-resident).
__global__ __launch_bounds__(256) void gemm2_kernel(
    const unsigned short* __restrict__ h_buf,  // [2T][2048] bf16
    const unsigned short* __restrict__ w2t,    // [E][1024][2048] bf16
    const int* __restrict__ cnt, const int* __restrict__ base,
    const int* __restrict__ tid_list, const float* __restrict__ tw_list,
    float* __restrict__ out) {                 // [T][1024] fp32
  __shared__ __align__(16) unsigned short As[128 * 64];
  __shared__ __align__(16) unsigned short Bs[128 * 64];

  const int e = blockIdx.x & 7;
  const int count = cnt[e];
  const int mt = (count + 127) >> 7;
  const int bs = base[e];

  const int t = threadIdx.x;
  const int wv = t >> 6, lane = t & 63;
  const int quad = lane >> 4, lr = lane & 15;
  const int wm = (wv & 1) * 64, wn = (wv >> 1) * 64;
  const int lr8 = lane >> 3, lc8 = lane & 7;
  const int chunk = lc8 ^ lr8;

  for (int idx = blockIdx.x >> 3; idx < mt * 8; idx += 176) {
    const int nl = idx & 3;         // n within half (4 of 8)
    int mr = idx >> 2;              // [0, 2*mt)
    int nh = 0;
    if (mr >= mt) { mr -= mt; nh = 1; }
    const int m0 = mr << 7;
    const int n0 = (nh * 4 + nl) << 7;

    const unsigned short* aptr[4];
    const unsigned short* bptr[4];
#pragma unroll
    for (int q = 0; q < 4; ++q) {
      int ar = m0 + wv * 32 + q * 8 + lr8;
      int ai = ar < count ? ar : count - 1;
      aptr[q] = h_buf + (size_t)(bs + ai) * 2048 + chunk * 8;
      int br = n0 + wv * 32 + q * 8 + lr8;
      bptr[q] = w2t + ((size_t)e * 1024 + br) * 2048 + chunk * 8;
    }
    unsigned short* aldsb = &As[wv * 2048];
    unsigned short* bldsb = &Bs[wv * 2048];

    floatx4 zero = {0.f, 0.f, 0.f, 0.f};
    floatx4 acc[4][4];
#pragma unroll
    for (int i = 0; i < 4; ++i)
#pragma unroll
      for (int j = 0; j < 4; ++j) acc[i][j] = zero;

    for (int k0 = 0; k0 < 2048; k0 += 64) {
      __syncthreads();
#pragma unroll
      for (int q = 0; q < 4; ++q) {
        async16(aptr[q] + k0, aldsb + q * 512);
        async16(bptr[q] + k0, bldsb + q * 512);
      }
      __syncthreads();
#pragma unroll
      for (int ks = 0; ks < 2; ++ks) {
        short8 af[4], bfv[4];
#pragma unroll
        for (int i = 0; i < 4; ++i) {
          int r = wm + i * 16 + lr;
          int pc = (ks * 4 + quad) ^ (lr & 7);
          af[i] = *(const short8*)&As[r * 64 + pc * 8];
        }
#pragma unroll
        for (int j = 0; j < 4; ++j) {
          int r = wn + j * 16 + lr;
          int pc = (ks * 4 + quad) ^ (lr & 7);
          bfv[j] = *(const short8*)&Bs[r * 64 + pc * 8];
        }
#pragma unroll
        for (int i = 0; i < 4; ++i)
#pragma unroll
          for (int j = 0; j < 4; ++j)
            acc[i][j] = __builtin_amdgcn_mfma_f32_16x16x32_bf16(af[i], bfv[j], acc[i][j], 0, 0, 0);
      }
    }

#pragma unroll
    for (int i = 0; i < 4; ++i) {
#pragma unroll
      for (int r = 0; r < 4; ++r) {
        int grow = m0 + wm + i * 16 + quad * 4 + r;
        if (grow < count) {
          int tok = tid_list[e * T_TOK + grow];
          float w = tw_list[e * T_TOK + grow];
          size_t rowoff = (size_t)tok * 1024;
#pragma unroll
          for (int j = 0; j < 4; ++j) {
            unsafeAtomicAdd(&out[rowoff + n0 + wn + j * 16 + lr], acc[i][j][r] * w);
          }
        }
      }
    }
  }
}

extern "C" void kernel_launch(void* const* d_in, const int* in_sizes, int n_in,
                              void* d_out, int out_size, void* d_ws, size_t ws_size,
                              hipStream_t stream) {
  const float* x   = (const float*)d_in[0];
  const float* rw1 = (const float*)d_in[1];
  const float* rw2 = (const float*)d_in[2];
  const float* W1  = (const float*)d_in[3];
  const float* W2  = (const float*)d_in[4];
  float* out = (float*)d_out;

  char* ws = (char*)d_ws;
  int*            cnt      = (int*)(ws + 0);        // 32 B
  int*            base     = (int*)(ws + 64);       // 32 B
  int*            fix_cnt  = (int*)(ws + 128);      // 4 B
  int*            tid_list = (int*)(ws + 512);      // 256 KB
  float*          tw_list  = (float*)(ws + 262656); // 256 KB
  unsigned short* xb       = (unsigned short*)(ws + 524800);    // 16 MB
  unsigned short* w1t      = (unsigned short*)(ws + 17302016);  // 32 MB
  unsigned short* w2t      = (unsigned short*)(ws + 50856448);  // 32 MB
  unsigned short* hbuf     = (unsigned short*)(ws + 84410880);  // 64 MB
  int*            tok_top  = (int*)(ws + 151519744);   // 64 KB
  float*          tok_w    = (float*)(ws + 151585280); // 64 KB
  int*            fix_list = (int*)(ws + 151650816);   // 32 KB

  hipMemsetAsync(d_out, 0, (size_t)T_TOK * 1024 * 4, stream);
  hipMemsetAsync(ws, 0, 192, stream);  // cnt, base, fix_cnt

  hipLaunchKernelGGL(router_fp32_kernel, dim3(1024), dim3(256), 0, stream,
                     x, rw1, rw2, tok_top, tok_w, fix_list, fix_cnt, xb);
  hipLaunchKernelGGL(router_fix_kernel, dim3(128), dim3(256), 0, stream,
                     x, rw1, rw2, fix_list, fix_cnt, tok_top, tok_w);
  hipLaunchKernelGGL(scatter_kernel, dim3(32), dim3(256), 0, stream,
                     tok_top, tok_w, cnt, tid_list, tw_list);
  hipLaunchKernelGGL(prefix_kernel, dim3(1), dim3(1), 0, stream, cnt, base);
  // W1: [e][1024][2048] -> w1t [e][2048][1024]; 512 tiles/expert, ylog=4
  hipLaunchKernelGGL(transpose_bf16_kernel, dim3(4096), dim3(256), 0, stream,
                     W1, w1t, 1024, 2048, 4);
  // W2: [e][2048][1024] -> w2t [e][1024][2048]; 512 tiles/expert, ylog=5
  hipLaunchKernelGGL(transpose_bf16_kernel, dim3(4096), dim3(256), 0, stream,
                     W2, w2t, 2048, 1024, 5);
  // Expert-affine grids: 8 XCDs x per-XCD slots (352 / 176); grid-stride
  // loop inside covers any routing imbalance.
  hipLaunchKernelGGL(gemm1_kernel, dim3(2816), dim3(256), 0, stream,
                     xb, w1t, cnt, base, tid_list, hbuf);
  hipLaunchKernelGGL(gemm2_kernel, dim3(1408), dim3(256), 0, stream,
                     hbuf, w2t, cnt, base, tid_list, tw_list, out);
}

// Round 7
// 605.697 us; speedup vs baseline: 1.0475x; 1.0475x over previous
//
#include <hip/hip_runtime.h>
#include <hip/hip_bf16.h>
#include <math.h>

#define T_TOK 8192
#define E_NUM 8
#define GAP_TAU 2e-3f

typedef __attribute__((ext_vector_type(8))) short short8;
typedef __attribute__((ext_vector_type(4))) float floatx4;
typedef __attribute__((ext_vector_type(2))) unsigned int uintx2;

__device__ __forceinline__ unsigned short f2bf(float f) {
  unsigned int u = __builtin_bit_cast(unsigned int, f);
  u += 0x7fffu + ((u >> 16) & 1u);
  return (unsigned short)(u >> 16);
}

// async global->LDS, 16B per lane; LDS dest = wave-uniform base + lane*16
__device__ __forceinline__ void async16(const unsigned short* g, unsigned short* l) {
  __builtin_amdgcn_global_load_lds(
      (const __attribute__((address_space(1))) void*)g,
      (__attribute__((address_space(3))) void*)l, 16, 0, 0);
}

// XCD-aware balanced tile map (r0 baseline, measured best 556us): xcd = flat&7,
// each XCD gets a contiguous band of ACTIVE m-tiles, n sweeps fastest.
__device__ __forceinline__ bool tile_map(int flat, const int* cnt, int nt_log2,
                                         int& e, int& m0, int& n0) {
  const int xcd = flat & 7;
  const int idx = flat >> 3;
  int mtp[E_NUM + 1];
  mtp[0] = 0;
#pragma unroll
  for (int q = 0; q < E_NUM; ++q) mtp[q + 1] = mtp[q] + ((cnt[q] + 127) >> 7);
  const int MT = mtp[E_NUM];
  const int band = (MT + 7) >> 3;
  const int i = idx >> nt_log2;
  if (i >= band) return false;
  const int g = xcd * band + i;
  if (g >= MT) return false;
  e = 0;
#pragma unroll
  for (int q = 0; q < E_NUM - 1; ++q) if (g >= mtp[q + 1]) e = q + 1;
  m0 = (g - mtp[e]) << 7;
  n0 = (idx & ((1 << nt_log2) - 1)) << 7;
  return true;
}

// ---------------- Router pass 1: fp32 logits, top-2, flag small-gap tokens ----
// xb (bf16 copy of x) stored NONTEMPORAL: consumed by gemm1 on other XCDs, so
// push lines out of this XCD's L2 toward L3 (clean) instead of leaving them
// dirty-remote (cross-XCD dirty probe is the slowest service path).
__global__ __launch_bounds__(256) void router_fp32_kernel(
    const float* __restrict__ x, const float* __restrict__ rw1,
    const float* __restrict__ rw2,
    int* __restrict__ tok_top, float* __restrict__ tok_w,
    int* __restrict__ fix_list, int* __restrict__ fix_cnt,
    unsigned short* __restrict__ xb) {
  __shared__ __align__(16) float xs[8][1024];  // 32 KB
  __shared__ float ph[128][8];                 // 4 KB
  __shared__ float hs[8][129];
  __shared__ float ls[8][8];
  const int t = threadIdx.x;
  const int tok0 = blockIdx.x * 8;

  {
    const float4* xsrc = (const float4*)(x + (size_t)tok0 * 1024);
    float4* xd = (float4*)&xs[0][0];
    uintx2* xbd = (uintx2*)(xb + (size_t)tok0 * 1024);
#pragma unroll
    for (int i = 0; i < 8; ++i) {
      float4 v = xsrc[t + i * 256];
      xd[t + i * 256] = v;
      ushort4 o;
      o.x = f2bf(v.x); o.y = f2bf(v.y); o.z = f2bf(v.z); o.w = f2bf(v.w);
      __builtin_nontemporal_store(__builtin_bit_cast(uintx2, o), &xbd[t + i * 256]);
    }
  }
  __syncthreads();

  const int j = t & 127, h = t >> 7;
  float acc[8];
#pragma unroll
  for (int tt = 0; tt < 8; ++tt) acc[tt] = 0.f;

  const int dbeg = h * 512, dend = dbeg + 512;
#pragma unroll 2
  for (int d0 = dbeg; d0 < dend; d0 += 4) {
    float w0 = rw1[(d0 + 0) * 128 + j];
    float w1 = rw1[(d0 + 1) * 128 + j];
    float w2 = rw1[(d0 + 2) * 128 + j];
    float w3 = rw1[(d0 + 3) * 128 + j];
    float4 xv[8];
#pragma unroll
    for (int tt = 0; tt < 8; ++tt) xv[tt] = *(const float4*)&xs[tt][d0];
#pragma unroll
    for (int tt = 0; tt < 8; ++tt) {
      acc[tt] = fmaf(xv[tt].x, w0, acc[tt]);
      acc[tt] = fmaf(xv[tt].y, w1, acc[tt]);
      acc[tt] = fmaf(xv[tt].z, w2, acc[tt]);
      acc[tt] = fmaf(xv[tt].w, w3, acc[tt]);
    }
  }
  if (h == 1) {
#pragma unroll
    for (int tt = 0; tt < 8; ++tt) ph[j][tt] = acc[tt];
  }
  __syncthreads();
  if (h == 0) {
#pragma unroll
    for (int tt = 0; tt < 8; ++tt) {
      float a = acc[tt] + ph[j][tt];
      hs[tt][j] = a / (1.f + expf(-a));
    }
  }
  __syncthreads();
  if (t < 64) {
    int tt = t >> 3, e = t & 7;
    float l = 0.f;
#pragma unroll 4
    for (int jj = 0; jj < 128; ++jj) l = fmaf(hs[tt][jj], rw2[jj * 8 + e], l);
    ls[tt][e] = l;
  }
  __syncthreads();
  if (t < 8) {
    int tt = t;
    float l[8];
#pragma unroll
    for (int e = 0; e < 8; ++e) l[e] = ls[tt][e];
    int i0 = 0;
#pragma unroll
    for (int e = 1; e < 8; ++e) if (l[e] > l[i0]) i0 = e;
    int i1 = (i0 == 0) ? 1 : 0;
#pragma unroll
    for (int e = 0; e < 8; ++e) if (e != i0 && l[e] > l[i1]) i1 = e;
    float v2 = -3.4e38f;
#pragma unroll
    for (int e = 0; e < 8; ++e) if (e != i0 && e != i1 && l[e] > v2) v2 = l[e];
    float gap = l[i1] - v2;
    float p = expf(l[i1] - l[i0]);
    float w0 = 1.f / (1.f + p);
    int tok = tok0 + tt;
    tok_top[2 * tok] = i0; tok_top[2 * tok + 1] = i1;
    tok_w[2 * tok] = w0;   tok_w[2 * tok + 1] = 1.f - w0;
    if (gap < GAP_TAU) { int pos = atomicAdd(fix_cnt, 1); fix_list[pos] = tok; }
  }
}

// ---------------- Router pass 2: exact fp64 recompute for flagged tokens ----
__global__ __launch_bounds__(256) void router_fix_kernel(
    const float* __restrict__ x, const float* __restrict__ rw1,
    const float* __restrict__ rw2, const int* __restrict__ fix_list,
    const int* __restrict__ fix_cnt,
    int* __restrict__ tok_top, float* __restrict__ tok_w) {
  __shared__ __align__(16) float xs[1024];
  __shared__ double red[128];
  __shared__ double hs[128];
  __shared__ double ls[8];
  const int t = threadIdx.x;
  const int nfix = *fix_cnt;
  for (int it = blockIdx.x; it < nfix; it += gridDim.x) {
    int tok = fix_list[it];
    ((float4*)xs)[t] = ((const float4*)(x + (size_t)tok * 1024))[t];
    __syncthreads();
    const int j = t & 127, h = t >> 7;
    double a0 = 0, a1 = 0, a2 = 0, a3 = 0;
    const int dbeg = h * 512;
    for (int d0 = dbeg; d0 < dbeg + 512; d0 += 4) {
      a0 = fma((double)xs[d0 + 0], (double)rw1[(d0 + 0) * 128 + j], a0);
      a1 = fma((double)xs[d0 + 1], (double)rw1[(d0 + 1) * 128 + j], a1);
      a2 = fma((double)xs[d0 + 2], (double)rw1[(d0 + 2) * 128 + j], a2);
      a3 = fma((double)xs[d0 + 3], (double)rw1[(d0 + 3) * 128 + j], a3);
    }
    double a = (a0 + a1) + (a2 + a3);
    if (h == 1) red[j] = a;
    __syncthreads();
    if (h == 0) {
      double s = a + red[j];
      hs[j] = s / (1.0 + exp(-s));
    }
    __syncthreads();
    if (t < 8) {
      int e = t;
      double l = 0;
      for (int jj = 0; jj < 128; ++jj) l = fma(hs[jj], (double)rw2[jj * 8 + e], l);
      ls[e] = l;
    }
    __syncthreads();
    if (t == 0) {
      double l[8];
#pragma unroll
      for (int e = 0; e < 8; ++e) l[e] = ls[e];
      int i0 = 0;
#pragma unroll
      for (int e = 1; e < 8; ++e) if (l[e] > l[i0]) i0 = e;
      int i1 = (i0 == 0) ? 1 : 0;
#pragma unroll
      for (int e = 0; e < 8; ++e) if (e != i0 && l[e] > l[i1]) i1 = e;
      double p = exp(l[i1] - l[i0]);
      double w0 = 1.0 / (1.0 + p);
      tok_top[2 * tok] = i0; tok_top[2 * tok + 1] = i1;
      tok_w[2 * tok] = (float)w0; tok_w[2 * tok + 1] = (float)(1.0 - w0);
    }
    __syncthreads();
  }
}

// ---------------- Scatter: build per-expert token lists (block-aggregated) ----
__global__ __launch_bounds__(256) void scatter_kernel(
    const int* __restrict__ tok_top, const float* __restrict__ tok_w,
    int* __restrict__ cnt, int* __restrict__ tid_list, float* __restrict__ tw_list) {
  __shared__ int hist[8], run[8];
  const int t = threadIdx.x;
  if (t < 8) hist[t] = 0;
  __syncthreads();
  const int tok = blockIdx.x * 256 + t;
  const int e0 = tok_top[2 * tok], e1 = tok_top[2 * tok + 1];
  atomicAdd(&hist[e0], 1);
  atomicAdd(&hist[e1], 1);
  __syncthreads();
  if (t < 8) run[t] = atomicAdd(&cnt[t], hist[t]);
  __syncthreads();
  int p0 = atomicAdd(&run[e0], 1);
  tid_list[e0 * T_TOK + p0] = tok; tw_list[e0 * T_TOK + p0] = tok_w[2 * tok];
  int p1 = atomicAdd(&run[e1], 1);
  tid_list[e1 * T_TOK + p1] = tok; tw_list[e1 * T_TOK + p1] = tok_w[2 * tok + 1];
}

__global__ void prefix_kernel(const int* __restrict__ cnt, int* __restrict__ base) {
  if (threadIdx.x == 0 && blockIdx.x == 0) {
    int s = 0;
    for (int e = 0; e < E_NUM; ++e) { base[e] = s; s += cnt[e]; }
  }
}

// ---------------- tiled transpose + convert: [e][R][C] fp32 -> [e][C][R] bf16 ----
// NONTEMPORAL output: w1t/w2t are consumed by gemm blocks on ALL XCDs; push
// lines to L3 clean instead of dirty-resident in the producer XCD's L2.
__global__ __launch_bounds__(256) void transpose_bf16_kernel(
    const float* __restrict__ in, unsigned short* __restrict__ out, int R, int C) {
  __shared__ unsigned short tile[64][65];
  const int e = blockIdx.z;
  const int r0 = blockIdx.y * 64, c0 = blockIdx.x * 64;
  const float* src = in + (size_t)e * R * C;
  unsigned short* dst = out + (size_t)e * R * C;
  const int t = threadIdx.x;
  const int cc = (t & 15) * 4;
#pragma unroll
  for (int p = 0; p < 4; ++p) {
    int r = p * 16 + (t >> 4);
    float4 v = *(const float4*)(src + (size_t)(r0 + r) * C + c0 + cc);
    tile[cc + 0][r] = f2bf(v.x);
    tile[cc + 1][r] = f2bf(v.y);
    tile[cc + 2][r] = f2bf(v.z);
    tile[cc + 3][r] = f2bf(v.w);
  }
  __syncthreads();
#pragma unroll
  for (int p = 0; p < 4; ++p) {
    int fr = p * 16 + (t >> 4);
    ushort4 o;
    o.x = tile[fr][cc + 0]; o.y = tile[fr][cc + 1];
    o.z = tile[fr][cc + 2]; o.w = tile[fr][cc + 3];
    __builtin_nontemporal_store(
        __builtin_bit_cast(uintx2, o),
        (uintx2*)(dst + (size_t)(c0 + fr) * R + r0 + cc));
  }
}

// ============ GEMM1: h[slot][f] = silu( x[tok][:] @ W1t[e][f][:] ) =============
// r0-exact. Epilogue h_buf stores NONTEMPORAL: hbuf is re-read by gemm2 blocks
// on other XCDs; dirty-remote L2 lines are the slowest read path.
__global__ __launch_bounds__(256) void gemm1_kernel(
    const unsigned short* __restrict__ xb,   // [T][1024] bf16
    const unsigned short* __restrict__ w1t,  // [E][2048][1024] bf16
    const int* __restrict__ cnt, const int* __restrict__ base,
    const int* __restrict__ tid_list,
    unsigned short* __restrict__ h_buf) {    // [2T][2048] bf16
  int e, m0, n0;
  if (!tile_map(blockIdx.x, cnt, 4, e, m0, n0)) return;  // NT=16
  const int count = cnt[e];
  const int bs = base[e];

  __shared__ __align__(16) unsigned short As[128 * 64];
  __shared__ __align__(16) unsigned short Bs[128 * 64];

  const int t = threadIdx.x;
  const int wv = t >> 6, lane = t & 63;
  const int quad = lane >> 4, lr = lane & 15;
  const int wm = (wv & 1) * 64, wn = (wv >> 1) * 64;
  const int lr8 = lane >> 3, lc8 = lane & 7;
  const int chunk = lc8 ^ lr8;

  const unsigned short* aptr[4];
  const unsigned short* bptr[4];
#pragma unroll
  for (int q = 0; q < 4; ++q) {
    int ar = m0 + wv * 32 + q * 8 + lr8;
    int ai = ar < count ? ar : count - 1;
    int tok = tid_list[e * T_TOK + ai];
    aptr[q] = xb + (size_t)tok * 1024 + chunk * 8;
    int br = n0 + wv * 32 + q * 8 + lr8;
    bptr[q] = w1t + ((size_t)e * 2048 + br) * 1024 + chunk * 8;
  }
  unsigned short* aldsb = &As[wv * 2048];
  unsigned short* bldsb = &Bs[wv * 2048];

  floatx4 zero = {0.f, 0.f, 0.f, 0.f};
  floatx4 acc[4][4];
#pragma unroll
  for (int i = 0; i < 4; ++i)
#pragma unroll
    for (int j = 0; j < 4; ++j) acc[i][j] = zero;

  for (int k0 = 0; k0 < 1024; k0 += 64) {
    __syncthreads();
#pragma unroll
    for (int q = 0; q < 4; ++q) {
      async16(aptr[q] + k0, aldsb + q * 512);
      async16(bptr[q] + k0, bldsb + q * 512);
    }
    __syncthreads();
#pragma unroll
    for (int ks = 0; ks < 2; ++ks) {
      short8 af[4], bfv[4];
#pragma unroll
      for (int i = 0; i < 4; ++i) {
        int r = wm + i * 16 + lr;
        int pc = (ks * 4 + quad) ^ (lr & 7);
        af[i] = *(const short8*)&As[r * 64 + pc * 8];
      }
#pragma unroll
      for (int j = 0; j < 4; ++j) {
        int r = wn + j * 16 + lr;
        int pc = (ks * 4 + quad) ^ (lr & 7);
        bfv[j] = *(const short8*)&Bs[r * 64 + pc * 8];
      }
#pragma unroll
      for (int i = 0; i < 4; ++i)
#pragma unroll
        for (int j = 0; j < 4; ++j)
          acc[i][j] = __builtin_amdgcn_mfma_f32_16x16x32_bf16(af[i], bfv[j], acc[i][j], 0, 0, 0);
    }
  }

#pragma unroll
  for (int i = 0; i < 4; ++i) {
#pragma unroll
    for (int r = 0; r < 4; ++r) {
      int grow = m0 + wm + i * 16 + quad * 4 + r;
      if (grow < count) {
        size_t rowoff = (size_t)(bs + grow) * 2048;
#pragma unroll
        for (int j = 0; j < 4; ++j) {
          float v = acc[i][j][r];
          float s = v / (1.0f + __expf(-v));
          __builtin_nontemporal_store(f2bf(s), &h_buf[rowoff + n0 + wn + j * 16 + lr]);
        }
      }
    }
  }
}

// ============ GEMM2: out[tok][:] += w * ( h[slot][:] @ W2t[e][d][:] ) ==========
__global__ __launch_bounds__(256) void gemm2_kernel(
    const unsigned short* __restrict__ h_buf,  // [2T][2048] bf16
    const unsigned short* __restrict__ w2t,    // [E][1024][2048] bf16
    const int* __restrict__ cnt, const int* __restrict__ base,
    const int* __restrict__ tid_list, const float* __restrict__ tw_list,
    float* __restrict__ out) {                 // [T][1024] fp32
  int e, m0, n0;
  if (!tile_map(blockIdx.x, cnt, 3, e, m0, n0)) return;  // NT=8
  const int count = cnt[e];
  const int bs = base[e];

  __shared__ __align__(16) unsigned short As[128 * 64];
  __shared__ __align__(16) unsigned short Bs[128 * 64];

  const int t = threadIdx.x;
  const int wv = t >> 6, lane = t & 63;
  const int quad = lane >> 4, lr = lane & 15;
  const int wm = (wv & 1) * 64, wn = (wv >> 1) * 64;
  const int lr8 = lane >> 3, lc8 = lane & 7;
  const int chunk = lc8 ^ lr8;

  const unsigned short* aptr[4];
  const unsigned short* bptr[4];
#pragma unroll
  for (int q = 0; q < 4; ++q) {
    int ar = m0 + wv * 32 + q * 8 + lr8;
    int ai = ar < count ? ar : count - 1;
    aptr[q] = h_buf + (size_t)(bs + ai) * 2048 + chunk * 8;
    int br = n0 + wv * 32 + q * 8 + lr8;
    bptr[q] = w2t + ((size_t)e * 1024 + br) * 2048 + chunk * 8;
  }
  unsigned short* aldsb = &As[wv * 2048];
  unsigned short* bldsb = &Bs[wv * 2048];

  floatx4 zero = {0.f, 0.f, 0.f, 0.f};
  floatx4 acc[4][4];
#pragma unroll
  for (int i = 0; i < 4; ++i)
#pragma unroll
    for (int j = 0; j < 4; ++j) acc[i][j] = zero;

  for (int k0 = 0; k0 < 2048; k0 += 64) {
    __syncthreads();
#pragma unroll
    for (int q = 0; q < 4; ++q) {
      async16(aptr[q] + k0, aldsb + q * 512);
      async16(bptr[q] + k0, bldsb + q * 512);
    }
    __syncthreads();
#pragma unroll
    for (int ks = 0; ks < 2; ++ks) {
      short8 af[4], bfv[4];
#pragma unroll
      for (int i = 0; i < 4; ++i) {
        int r = wm + i * 16 + lr;
        int pc = (ks * 4 + quad) ^ (lr & 7);
        af[i] = *(const short8*)&As[r * 64 + pc * 8];
      }
#pragma unroll
      for (int j = 0; j < 4; ++j) {
        int r = wn + j * 16 + lr;
        int pc = (ks * 4 + quad) ^ (lr & 7);
        bfv[j] = *(const short8*)&Bs[r * 64 + pc * 8];
      }
#pragma unroll
      for (int i = 0; i < 4; ++i)
#pragma unroll
        for (int j = 0; j < 4; ++j)
          acc[i][j] = __builtin_amdgcn_mfma_f32_16x16x32_bf16(af[i], bfv[j], acc[i][j], 0, 0, 0);
    }
  }

#pragma unroll
  for (int i = 0; i < 4; ++i) {
#pragma unroll
    for (int r = 0; r < 4; ++r) {
      int grow = m0 + wm + i * 16 + quad * 4 + r;
      if (grow < count) {
        int tok = tid_list[e * T_TOK + grow];
        float w = tw_list[e * T_TOK + grow];
        size_t rowoff = (size_t)tok * 1024;
#pragma unroll
        for (int j = 0; j < 4; ++j) {
          unsafeAtomicAdd(&out[rowoff + n0 + wn + j * 16 + lr], acc[i][j][r] * w);
        }
      }
    }
  }
}

extern "C" void kernel_launch(void* const* d_in, const int* in_sizes, int n_in,
                              void* d_out, int out_size, void* d_ws, size_t ws_size,
                              hipStream_t stream) {
  const float* x   = (const float*)d_in[0];
  const float* rw1 = (const float*)d_in[1];
  const float* rw2 = (const float*)d_in[2];
  const float* W1  = (const float*)d_in[3];
  const float* W2  = (const float*)d_in[4];
  float* out = (float*)d_out;

  char* ws = (char*)d_ws;
  int*            cnt      = (int*)(ws + 0);        // 32 B
  int*            base     = (int*)(ws + 64);       // 32 B
  int*            fix_cnt  = (int*)(ws + 128);      // 4 B
  int*            tid_list = (int*)(ws + 512);      // 256 KB
  float*          tw_list  = (float*)(ws + 262656); // 256 KB
  unsigned short* xb       = (unsigned short*)(ws + 524800);    // 16 MB
  unsigned short* w1t      = (unsigned short*)(ws + 17302016);  // 32 MB
  unsigned short* w2t      = (unsigned short*)(ws + 50856448);  // 32 MB
  unsigned short* hbuf     = (unsigned short*)(ws + 84410880);  // 64 MB
  int*            tok_top  = (int*)(ws + 151519744);   // 64 KB
  float*          tok_w    = (float*)(ws + 151585280); // 64 KB
  int*            fix_list = (int*)(ws + 151650816);   // 32 KB

  hipMemsetAsync(d_out, 0, (size_t)T_TOK * 1024 * 4, stream);
  hipMemsetAsync(ws, 0, 192, stream);  // cnt, base, fix_cnt

  hipLaunchKernelGGL(router_fp32_kernel, dim3(1024), dim3(256), 0, stream,
                     x, rw1, rw2, tok_top, tok_w, fix_list, fix_cnt, xb);
  hipLaunchKernelGGL(router_fix_kernel, dim3(128), dim3(256), 0, stream,
                     x, rw1, rw2, fix_list, fix_cnt, tok_top, tok_w);
  hipLaunchKernelGGL(scatter_kernel, dim3(32), dim3(256), 0, stream,
                     tok_top, tok_w, cnt, tid_list, tw_list);
  hipLaunchKernelGGL(prefix_kernel, dim3(1), dim3(1), 0, stream, cnt, base);
  hipLaunchKernelGGL(transpose_bf16_kernel, dim3(32, 16, 8), dim3(256), 0, stream,
                     W1, w1t, 1024, 2048);
  hipLaunchKernelGGL(transpose_bf16_kernel, dim3(16, 32, 8), dim3(256), 0, stream,
                     W2, w2t, 2048, 1024);
  // grids: 8 XCDs * band(<=17) * NT  ->  8*17*16 = 2176 , 8*17*8 = 1088
  hipLaunchKernelGGL(gemm1_kernel, dim3(2176), dim3(256), 0, stream,
                     xb, w1t, cnt, base, tid_list, hbuf);
  hipLaunchKernelGGL(gemm2_kernel, dim3(1088), dim3(256), 0, stream,
                     hbuf, w2t, cnt, base, tid_list, tw_list, out);
}

// Round 8
// 528.577 us; speedup vs baseline: 1.2003x; 1.1459x over previous
//
#include <hip/hip_runtime.h>
#include <hip/hip_bf16.h>
#include <math.h>

#define T_TOK 8192
#define E_NUM 8
#define GAP_TAU 2e-3f

typedef __attribute__((ext_vector_type(8))) short short8;
typedef __attribute__((ext_vector_type(4))) float floatx4;

__device__ __forceinline__ unsigned short f2bf(float f) {
  unsigned int u = __builtin_bit_cast(unsigned int, f);
  u += 0x7fffu + ((u >> 16) & 1u);
  return (unsigned short)(u >> 16);
}

// async global->LDS, 16B per lane; LDS dest = wave-uniform base + lane*16
__device__ __forceinline__ void async16(const unsigned short* g, unsigned short* l) {
  __builtin_amdgcn_global_load_lds(
      (const __attribute__((address_space(1))) void*)g,
      (__attribute__((address_space(3))) void*)l, 16, 0, 0);
}

// XCD-aware balanced tile map (r0 baseline, measured best 556us): xcd = flat&7,
// each XCD gets a contiguous band of ACTIVE m-tiles, n sweeps fastest.
__device__ __forceinline__ bool tile_map(int flat, const int* cnt, int nt_log2,
                                         int& e, int& m0, int& n0) {
  const int xcd = flat & 7;
  const int idx = flat >> 3;
  int mtp[E_NUM + 1];
  mtp[0] = 0;
#pragma unroll
  for (int q = 0; q < E_NUM; ++q) mtp[q + 1] = mtp[q] + ((cnt[q] + 127) >> 7);
  const int MT = mtp[E_NUM];
  const int band = (MT + 7) >> 3;
  const int i = idx >> nt_log2;
  if (i >= band) return false;
  const int g = xcd * band + i;
  if (g >= MT) return false;
  e = 0;
#pragma unroll
  for (int q = 0; q < E_NUM - 1; ++q) if (g >= mtp[q + 1]) e = q + 1;
  m0 = (g - mtp[e]) << 7;
  n0 = (idx & ((1 << nt_log2) - 1)) << 7;
  return true;
}

// ---------------- Fused prep: router + W1-transpose + W2-transpose ----------
// The three roles are data-independent (router: x/rw1/rw2; transposes: W1/W2)
// but were serialized as 3 launches on one stream (~90-110 us end-to-end).
// One kernel with block-range role dispatch runs them CONCURRENTLY.
// LDS: union of router's 40.3 KB and transpose's 8.3 KB tile.

__device__ __forceinline__ void router_body(
    char* smem, int blk,
    const float* __restrict__ x, const float* __restrict__ rw1,
    const float* __restrict__ rw2,
    int* __restrict__ tok_top, float* __restrict__ tok_w,
    int* __restrict__ fix_list, int* __restrict__ fix_cnt,
    unsigned short* __restrict__ xb) {
  float (*xs)[1024] = reinterpret_cast<float(*)[1024]>(smem);           // 32 KB
  float (*ph)[8]    = reinterpret_cast<float(*)[8]>(smem + 32768);      // 4 KB
  float (*hs)[129]  = reinterpret_cast<float(*)[129]>(smem + 36864);    // 4.1 KB
  float (*ls)[8]    = reinterpret_cast<float(*)[8]>(smem + 40992);      // 256 B
  const int t = threadIdx.x;
  const int tok0 = blk * 8;

  {
    const float4* xsrc = (const float4*)(x + (size_t)tok0 * 1024);
    float4* xd = (float4*)&xs[0][0];
    ushort4* xbd = (ushort4*)(xb + (size_t)tok0 * 1024);
#pragma unroll
    for (int i = 0; i < 8; ++i) {
      float4 v = xsrc[t + i * 256];
      xd[t + i * 256] = v;
      ushort4 o;
      o.x = f2bf(v.x); o.y = f2bf(v.y); o.z = f2bf(v.z); o.w = f2bf(v.w);
      xbd[t + i * 256] = o;
    }
  }
  __syncthreads();

  const int j = t & 127, h = t >> 7;
  float acc[8];
#pragma unroll
  for (int tt = 0; tt < 8; ++tt) acc[tt] = 0.f;

  const int dbeg = h * 512, dend = dbeg + 512;
#pragma unroll 2
  for (int d0 = dbeg; d0 < dend; d0 += 4) {
    float w0 = rw1[(d0 + 0) * 128 + j];
    float w1 = rw1[(d0 + 1) * 128 + j];
    float w2 = rw1[(d0 + 2) * 128 + j];
    float w3 = rw1[(d0 + 3) * 128 + j];
    float4 xv[8];
#pragma unroll
    for (int tt = 0; tt < 8; ++tt) xv[tt] = *(const float4*)&xs[tt][d0];
#pragma unroll
    for (int tt = 0; tt < 8; ++tt) {
      acc[tt] = fmaf(xv[tt].x, w0, acc[tt]);
      acc[tt] = fmaf(xv[tt].y, w1, acc[tt]);
      acc[tt] = fmaf(xv[tt].z, w2, acc[tt]);
      acc[tt] = fmaf(xv[tt].w, w3, acc[tt]);
    }
  }
  if (h == 1) {
#pragma unroll
    for (int tt = 0; tt < 8; ++tt) ph[j][tt] = acc[tt];
  }
  __syncthreads();
  if (h == 0) {
#pragma unroll
    for (int tt = 0; tt < 8; ++tt) {
      float a = acc[tt] + ph[j][tt];
      hs[tt][j] = a / (1.f + expf(-a));
    }
  }
  __syncthreads();
  if (t < 64) {
    int tt = t >> 3, e = t & 7;
    float l = 0.f;
#pragma unroll 4
    for (int jj = 0; jj < 128; ++jj) l = fmaf(hs[tt][jj], rw2[jj * 8 + e], l);
    ls[tt][e] = l;
  }
  __syncthreads();
  if (t < 8) {
    int tt = t;
    float l[8];
#pragma unroll
    for (int e = 0; e < 8; ++e) l[e] = ls[tt][e];
    int i0 = 0;
#pragma unroll
    for (int e = 1; e < 8; ++e) if (l[e] > l[i0]) i0 = e;
    int i1 = (i0 == 0) ? 1 : 0;
#pragma unroll
    for (int e = 0; e < 8; ++e) if (e != i0 && l[e] > l[i1]) i1 = e;
    float v2 = -3.4e38f;
#pragma unroll
    for (int e = 0; e < 8; ++e) if (e != i0 && e != i1 && l[e] > v2) v2 = l[e];
    float gap = l[i1] - v2;
    float p = expf(l[i1] - l[i0]);
    float w0 = 1.f / (1.f + p);
    int tok = tok0 + tt;
    tok_top[2 * tok] = i0; tok_top[2 * tok + 1] = i1;
    tok_w[2 * tok] = w0;   tok_w[2 * tok + 1] = 1.f - w0;
    if (gap < GAP_TAU) { int pos = atomicAdd(fix_cnt, 1); fix_list[pos] = tok; }
  }
}

__device__ __forceinline__ void transpose_body(
    char* smem, const float* __restrict__ in, unsigned short* __restrict__ out,
    int R, int C, int e, int r0, int c0) {
  unsigned short (*tile)[65] = reinterpret_cast<unsigned short(*)[65]>(smem);
  const float* src = in + (size_t)e * R * C;
  unsigned short* dst = out + (size_t)e * R * C;
  const int t = threadIdx.x;
  const int cc = (t & 15) * 4;
#pragma unroll
  for (int p = 0; p < 4; ++p) {
    int r = p * 16 + (t >> 4);
    float4 v = *(const float4*)(src + (size_t)(r0 + r) * C + c0 + cc);
    tile[cc + 0][r] = f2bf(v.x);
    tile[cc + 1][r] = f2bf(v.y);
    tile[cc + 2][r] = f2bf(v.z);
    tile[cc + 3][r] = f2bf(v.w);
  }
  __syncthreads();
#pragma unroll
  for (int p = 0; p < 4; ++p) {
    int fr = p * 16 + (t >> 4);
    ushort4 o;
    o.x = tile[fr][cc + 0]; o.y = tile[fr][cc + 1];
    o.z = tile[fr][cc + 2]; o.w = tile[fr][cc + 3];
    *(ushort4*)(dst + (size_t)(c0 + fr) * R + r0 + cc) = o;
  }
}

__global__ __launch_bounds__(256) void prep_kernel(
    const float* __restrict__ x, const float* __restrict__ rw1,
    const float* __restrict__ rw2,
    int* __restrict__ tok_top, float* __restrict__ tok_w,
    int* __restrict__ fix_list, int* __restrict__ fix_cnt,
    unsigned short* __restrict__ xb,
    const float* __restrict__ W1, unsigned short* __restrict__ w1t,
    const float* __restrict__ W2, unsigned short* __restrict__ w2t) {
  __shared__ __align__(16) char smem[41248];
  const int b = blockIdx.x;
  if (b < 1024) {
    router_body(smem, b, x, rw1, rw2, tok_top, tok_w, fix_list, fix_cnt, xb);
  } else if (b < 5120) {
    // W1 [e][1024][2048] -> w1t [e][2048][1024]; 512 tiles/expert (32c x 16r)
    const int b2 = b - 1024;
    const int c0 = (b2 & 31) * 64;
    const int r0 = ((b2 >> 5) & 15) * 64;
    const int e  = b2 >> 9;
    transpose_body(smem, W1, w1t, 1024, 2048, e, r0, c0);
  } else {
    // W2 [e][2048][1024] -> w2t [e][1024][2048]; 512 tiles/expert (16c x 32r)
    const int b3 = b - 5120;
    const int c0 = (b3 & 15) * 64;
    const int r0 = ((b3 >> 4) & 31) * 64;
    const int e  = b3 >> 9;
    transpose_body(smem, W2, w2t, 2048, 1024, e, r0, c0);
  }
}

// ---------------- Router pass 2: exact fp64 recompute for flagged tokens ----
__global__ __launch_bounds__(256) void router_fix_kernel(
    const float* __restrict__ x, const float* __restrict__ rw1,
    const float* __restrict__ rw2, const int* __restrict__ fix_list,
    const int* __restrict__ fix_cnt,
    int* __restrict__ tok_top, float* __restrict__ tok_w) {
  __shared__ __align__(16) float xs[1024];
  __shared__ double red[128];
  __shared__ double hs[128];
  __shared__ double ls[8];
  const int t = threadIdx.x;
  const int nfix = *fix_cnt;
  for (int it = blockIdx.x; it < nfix; it += gridDim.x) {
    int tok = fix_list[it];
    ((float4*)xs)[t] = ((const float4*)(x + (size_t)tok * 1024))[t];
    __syncthreads();
    const int j = t & 127, h = t >> 7;
    double a0 = 0, a1 = 0, a2 = 0, a3 = 0;
    const int dbeg = h * 512;
    for (int d0 = dbeg; d0 < dbeg + 512; d0 += 4) {
      a0 = fma((double)xs[d0 + 0], (double)rw1[(d0 + 0) * 128 + j], a0);
      a1 = fma((double)xs[d0 + 1], (double)rw1[(d0 + 1) * 128 + j], a1);
      a2 = fma((double)xs[d0 + 2], (double)rw1[(d0 + 2) * 128 + j], a2);
      a3 = fma((double)xs[d0 + 3], (double)rw1[(d0 + 3) * 128 + j], a3);
    }
    double a = (a0 + a1) + (a2 + a3);
    if (h == 1) red[j] = a;
    __syncthreads();
    if (h == 0) {
      double s = a + red[j];
      hs[j] = s / (1.0 + exp(-s));
    }
    __syncthreads();
    if (t < 8) {
      int e = t;
      double l = 0;
      for (int jj = 0; jj < 128; ++jj) l = fma(hs[jj], (double)rw2[jj * 8 + e], l);
      ls[e] = l;
    }
    __syncthreads();
    if (t == 0) {
      double l[8];
#pragma unroll
      for (int e = 0; e < 8; ++e) l[e] = ls[e];
      int i0 = 0;
#pragma unroll
      for (int e = 1; e < 8; ++e) if (l[e] > l[i0]) i0 = e;
      int i1 = (i0 == 0) ? 1 : 0;
#pragma unroll
      for (int e = 0; e < 8; ++e) if (e != i0 && l[e] > l[i1]) i1 = e;
      double p = exp(l[i1] - l[i0]);
      double w0 = 1.0 / (1.0 + p);
      tok_top[2 * tok] = i0; tok_top[2 * tok + 1] = i1;
      tok_w[2 * tok] = (float)w0; tok_w[2 * tok + 1] = (float)(1.0 - w0);
    }
    __syncthreads();
  }
}

// ---------------- Scatter: build per-expert token lists (block-aggregated) ----
__global__ __launch_bounds__(256) void scatter_kernel(
    const int* __restrict__ tok_top, const float* __restrict__ tok_w,
    int* __restrict__ cnt, int* __restrict__ tid_list, float* __restrict__ tw_list) {
  __shared__ int hist[8], run[8];
  const int t = threadIdx.x;
  if (t < 8) hist[t] = 0;
  __syncthreads();
  const int tok = blockIdx.x * 256 + t;
  const int e0 = tok_top[2 * tok], e1 = tok_top[2 * tok + 1];
  atomicAdd(&hist[e0], 1);
  atomicAdd(&hist[e1], 1);
  __syncthreads();
  if (t < 8) run[t] = atomicAdd(&cnt[t], hist[t]);
  __syncthreads();
  int p0 = atomicAdd(&run[e0], 1);
  tid_list[e0 * T_TOK + p0] = tok; tw_list[e0 * T_TOK + p0] = tok_w[2 * tok];
  int p1 = atomicAdd(&run[e1], 1);
  tid_list[e1 * T_TOK + p1] = tok; tw_list[e1 * T_TOK + p1] = tok_w[2 * tok + 1];
}

__global__ void prefix_kernel(const int* __restrict__ cnt, int* __restrict__ base) {
  if (threadIdx.x == 0 && blockIdx.x == 0) {
    int s = 0;
    for (int e = 0; e < E_NUM; ++e) { base[e] = s; s += cnt[e]; }
  }
}

// ============ GEMM1: h[slot][f] = silu( x[tok][:] @ W1t[e][f][:] ) =============
__global__ __launch_bounds__(256) void gemm1_kernel(
    const unsigned short* __restrict__ xb,   // [T][1024] bf16
    const unsigned short* __restrict__ w1t,  // [E][2048][1024] bf16
    const int* __restrict__ cnt, const int* __restrict__ base,
    const int* __restrict__ tid_list,
    unsigned short* __restrict__ h_buf) {    // [2T][2048] bf16
  int e, m0, n0;
  if (!tile_map(blockIdx.x, cnt, 4, e, m0, n0)) return;  // NT=16
  const int count = cnt[e];
  const int bs = base[e];

  __shared__ __align__(16) unsigned short As[128 * 64];
  __shared__ __align__(16) unsigned short Bs[128 * 64];

  const int t = threadIdx.x;
  const int wv = t >> 6, lane = t & 63;
  const int quad = lane >> 4, lr = lane & 15;
  const int wm = (wv & 1) * 64, wn = (wv >> 1) * 64;
  const int lr8 = lane >> 3, lc8 = lane & 7;
  const int chunk = lc8 ^ lr8;

  const unsigned short* aptr[4];
  const unsigned short* bptr[4];
#pragma unroll
  for (int q = 0; q < 4; ++q) {
    int ar = m0 + wv * 32 + q * 8 + lr8;
    int ai = ar < count ? ar : count - 1;
    int tok = tid_list[e * T_TOK + ai];
    aptr[q] = xb + (size_t)tok * 1024 + chunk * 8;
    int br = n0 + wv * 32 + q * 8 + lr8;
    bptr[q] = w1t + ((size_t)e * 2048 + br) * 1024 + chunk * 8;
  }
  unsigned short* aldsb = &As[wv * 2048];
  unsigned short* bldsb = &Bs[wv * 2048];

  floatx4 zero = {0.f, 0.f, 0.f, 0.f};
  floatx4 acc[4][4];
#pragma unroll
  for (int i = 0; i < 4; ++i)
#pragma unroll
    for (int j = 0; j < 4; ++j) acc[i][j] = zero;

  for (int k0 = 0; k0 < 1024; k0 += 64) {
    __syncthreads();
#pragma unroll
    for (int q = 0; q < 4; ++q) {
      async16(aptr[q] + k0, aldsb + q * 512);
      async16(bptr[q] + k0, bldsb + q * 512);
    }
    __syncthreads();
#pragma unroll
    for (int ks = 0; ks < 2; ++ks) {
      short8 af[4], bfv[4];
#pragma unroll
      for (int i = 0; i < 4; ++i) {
        int r = wm + i * 16 + lr;
        int pc = (ks * 4 + quad) ^ (lr & 7);
        af[i] = *(const short8*)&As[r * 64 + pc * 8];
      }
#pragma unroll
      for (int j = 0; j < 4; ++j) {
        int r = wn + j * 16 + lr;
        int pc = (ks * 4 + quad) ^ (lr & 7);
        bfv[j] = *(const short8*)&Bs[r * 64 + pc * 8];
      }
#pragma unroll
      for (int i = 0; i < 4; ++i)
#pragma unroll
        for (int j = 0; j < 4; ++j)
          acc[i][j] = __builtin_amdgcn_mfma_f32_16x16x32_bf16(af[i], bfv[j], acc[i][j], 0, 0, 0);
    }
  }

#pragma unroll
  for (int i = 0; i < 4; ++i) {
#pragma unroll
    for (int r = 0; r < 4; ++r) {
      int grow = m0 + wm + i * 16 + quad * 4 + r;
      if (grow < count) {
        size_t rowoff = (size_t)(bs + grow) * 2048;
#pragma unroll
        for (int j = 0; j < 4; ++j) {
          float v = acc[i][j][r];
          float s = v / (1.0f + __expf(-v));
          h_buf[rowoff + n0 + wn + j * 16 + lr] = f2bf(s);
        }
      }
    }
  }
}

// ============ GEMM2: out[tok][:] += w * ( h[slot][:] @ W2t[e][d][:] ) ==========
__global__ __launch_bounds__(256) void gemm2_kernel(
    const unsigned short* __restrict__ h_buf,  // [2T][2048] bf16
    const unsigned short* __restrict__ w2t,    // [E][1024][2048] bf16
    const int* __restrict__ cnt, const int* __restrict__ base,
    const int* __restrict__ tid_list, const float* __restrict__ tw_list,
    float* __restrict__ out) {                 // [T][1024] fp32
  int e, m0, n0;
  if (!tile_map(blockIdx.x, cnt, 3, e, m0, n0)) return;  // NT=8
  const int count = cnt[e];
  const int bs = base[e];

  __shared__ __align__(16) unsigned short As[128 * 64];
  __shared__ __align__(16) unsigned short Bs[128 * 64];

  const int t = threadIdx.x;
  const int wv = t >> 6, lane = t & 63;
  const int quad = lane >> 4, lr = lane & 15;
  const int wm = (wv & 1) * 64, wn = (wv >> 1) * 64;
  const int lr8 = lane >> 3, lc8 = lane & 7;
  const int chunk = lc8 ^ lr8;

  const unsigned short* aptr[4];
  const unsigned short* bptr[4];
#pragma unroll
  for (int q = 0; q < 4; ++q) {
    int ar = m0 + wv * 32 + q * 8 + lr8;
    int ai = ar < count ? ar : count - 1;
    aptr[q] = h_buf + (size_t)(bs + ai) * 2048 + chunk * 8;
    int br = n0 + wv * 32 + q * 8 + lr8;
    bptr[q] = w2t + ((size_t)e * 1024 + br) * 2048 + chunk * 8;
  }
  unsigned short* aldsb = &As[wv * 2048];
  unsigned short* bldsb = &Bs[wv * 2048];

  floatx4 zero = {0.f, 0.f, 0.f, 0.f};
  floatx4 acc[4][4];
#pragma unroll
  for (int i = 0; i < 4; ++i)
#pragma unroll
    for (int j = 0; j < 4; ++j) acc[i][j] = zero;

  for (int k0 = 0; k0 < 2048; k0 += 64) {
    __syncthreads();
#pragma unroll
    for (int q = 0; q < 4; ++q) {
      async16(aptr[q] + k0, aldsb + q * 512);
      async16(bptr[q] + k0, bldsb + q * 512);
    }
    __syncthreads();
#pragma unroll
    for (int ks = 0; ks < 2; ++ks) {
      short8 af[4], bfv[4];
#pragma unroll
      for (int i = 0; i < 4; ++i) {
        int r = wm + i * 16 + lr;
        int pc = (ks * 4 + quad) ^ (lr & 7);
        af[i] = *(const short8*)&As[r * 64 + pc * 8];
      }
#pragma unroll
      for (int j = 0; j < 4; ++j) {
        int r = wn + j * 16 + lr;
        int pc = (ks * 4 + quad) ^ (lr & 7);
        bfv[j] = *(const short8*)&Bs[r * 64 + pc * 8];
      }
#pragma unroll
      for (int i = 0; i < 4; ++i)
#pragma unroll
        for (int j = 0; j < 4; ++j)
          acc[i][j] = __builtin_amdgcn_mfma_f32_16x16x32_bf16(af[i], bfv[j], acc[i][j], 0, 0, 0);
    }
  }

#pragma unroll
  for (int i = 0; i < 4; ++i) {
#pragma unroll
    for (int r = 0; r < 4; ++r) {
      int grow = m0 + wm + i * 16 + quad * 4 + r;
      if (grow < count) {
        int tok = tid_list[e * T_TOK + grow];
        float w = tw_list[e * T_TOK + grow];
        size_t rowoff = (size_t)tok * 1024;
#pragma unroll
        for (int j = 0; j < 4; ++j) {
          unsafeAtomicAdd(&out[rowoff + n0 + wn + j * 16 + lr], acc[i][j][r] * w);
        }
      }
    }
  }
}

extern "C" void kernel_launch(void* const* d_in, const int* in_sizes, int n_in,
                              void* d_out, int out_size, void* d_ws, size_t ws_size,
                              hipStream_t stream) {
  const float* x   = (const float*)d_in[0];
  const float* rw1 = (const float*)d_in[1];
  const float* rw2 = (const float*)d_in[2];
  const float* W1  = (const float*)d_in[3];
  const float* W2  = (const float*)d_in[4];
  float* out = (float*)d_out;

  char* ws = (char*)d_ws;
  int*            cnt      = (int*)(ws + 0);        // 32 B
  int*            base     = (int*)(ws + 64);       // 32 B
  int*            fix_cnt  = (int*)(ws + 128);      // 4 B
  int*            tid_list = (int*)(ws + 512);      // 256 KB
  float*          tw_list  = (float*)(ws + 262656); // 256 KB
  unsigned short* xb       = (unsigned short*)(ws + 524800);    // 16 MB
  unsigned short* w1t      = (unsigned short*)(ws + 17302016);  // 32 MB
  unsigned short* w2t      = (unsigned short*)(ws + 50856448);  // 32 MB
  unsigned short* hbuf     = (unsigned short*)(ws + 84410880);  // 64 MB
  int*            tok_top  = (int*)(ws + 151519744);   // 64 KB
  float*          tok_w    = (float*)(ws + 151585280); // 64 KB
  int*            fix_list = (int*)(ws + 151650816);   // 32 KB

  hipMemsetAsync(d_out, 0, (size_t)T_TOK * 1024 * 4, stream);
  hipMemsetAsync(ws, 0, 192, stream);  // cnt, base, fix_cnt

  // Fused router + both weight transposes: 1024 + 4096 + 4096 blocks.
  hipLaunchKernelGGL(prep_kernel, dim3(9216), dim3(256), 0, stream,
                     x, rw1, rw2, tok_top, tok_w, fix_list, fix_cnt, xb,
                     W1, w1t, W2, w2t);
  hipLaunchKernelGGL(router_fix_kernel, dim3(128), dim3(256), 0, stream,
                     x, rw1, rw2, fix_list, fix_cnt, tok_top, tok_w);
  hipLaunchKernelGGL(scatter_kernel, dim3(32), dim3(256), 0, stream,
                     tok_top, tok_w, cnt, tid_list, tw_list);
  hipLaunchKernelGGL(prefix_kernel, dim3(1), dim3(1), 0, stream, cnt, base);
  // grids: 8 XCDs * band(<=17) * NT  ->  8*17*16 = 2176 , 8*17*8 = 1088
  hipLaunchKernelGGL(gemm1_kernel, dim3(2176), dim3(256), 0, stream,
                     xb, w1t, cnt, base, tid_list, hbuf);
  hipLaunchKernelGGL(gemm2_kernel, dim3(1088), dim3(256), 0, stream,
                     hbuf, w2t, cnt, base, tid_list, tw_list, out);
}